// Round 18
// baseline (196.225 us; speedup 1.0000x reference)
//
#include <hip/hip_runtime.h>
#include <hip/hip_bf16.h>
#include <math.h>

#define N_NODES 50000
#define N_EDGES 400000
#define IN_DIM 256
#define HID 64
#define HEADS 8
#define OUT_DIM 256
#define NEG_SLOPE 0.2f
#define BUCKET 64   // max in-degree capacity; P(exceed)<1e-30 for this input

// prep ranges: cvt_w | cvt_wo | fillhist
#define CVTW_BLOCKS 512               // 131072/256 exact
#define CVTWO_BLOCKS 512
#define FILL_BLOCKS 1563

typedef __attribute__((ext_vector_type(8))) short bf16x8;
typedef __attribute__((ext_vector_type(4))) float f32x4;

// RNE float->bf16
static __device__ __forceinline__ unsigned short f2bf(float f) {
    unsigned int u = __float_as_uint(f);
    unsigned int r = (u + 0x7fffu + ((u >> 16) & 1u)) >> 16;
    return (unsigned short)r;
}
static __device__ __forceinline__ float bf2f(unsigned short s) {
    return __uint_as_float((unsigned int)s << 16);
}
// convert 8 contiguous floats -> bf16x8
static __device__ __forceinline__ bf16x8 cvt8(const float* __restrict__ p) {
    bf16x8 r;
    #pragma unroll
    for (int j = 0; j < 8; ++j) r[j] = (short)f2bf(p[j]);
    return r;
}

// ---------------------------------------------------------------------------
// Fused prologue: cvt_w | cvt_wo | bucket-CSR fillhist by blockIdx range.
// ---------------------------------------------------------------------------
__global__ __launch_bounds__(256) void prep_kernel(
    const float* __restrict__ W, unsigned short* __restrict__ Wt,
    const float* __restrict__ Wo, unsigned short* __restrict__ Wot,
    const int* __restrict__ ei, int* __restrict__ deg,
    int* __restrict__ csr)
{
    const int b = blockIdx.x;
    if (b < CVTW_BLOCKS) {
        // W[hd][k][o] -> Wt[hd*64+o][k]
        const int i = b * 256 + threadIdx.x;
        const int hd = i >> 14;
        const int o  = (i >> 8) & 63;
        const int k  = i & 255;
        Wt[i] = f2bf(W[((size_t)hd * IN_DIM + k) * HID + o]);
    } else if (b < CVTW_BLOCKS + CVTWO_BLOCKS) {
        // Wo[k][n] -> Wot[n][k]
        const int i = (b - CVTW_BLOCKS) * 256 + threadIdx.x;
        const int n = i >> 9;
        const int k = i & 511;
        Wot[i] = f2bf(Wo[(size_t)k * OUT_DIM + n]);
    } else {
        // bucket-CSR: pos = atomicAdd(deg[tgt]); csr[tgt*BUCKET+pos] = src
        const int e = (b - CVTW_BLOCKS - CVTWO_BLOCKS) * 256 + threadIdx.x;
        if (e < N_EDGES) {
            const int src = ei[e];
            const int tgt = ei[N_EDGES + e];
            const int pos = atomicAdd(&deg[tgt], 1);
            if (pos < BUCKET) csr[tgt * BUCKET + pos] = src;
        }
    }
}

// ---------------------------------------------------------------------------
// Unified MFMA GEMM v3 (validated R13-R17): C[M][LDC] = A[M][K] @ Bt[N][K]^T
// Tile 128x256, BK=64, 512 thr = 8 waves (2M x 4N), acc[4][4],
// 32 MFMAs per barrier pair. CVTA=1: A f32 -> bf16 in staging.
// Fragment-order LDS: unit(row,g)=((row>>4)*8+g)*16+(row&15); frag read
// = units R*128 + kk*64 + lane (lane-linear, conflict-free).
// EPI 0: store C bf16.  EPI 1: +bias, elu, store f32.
// ---------------------------------------------------------------------------
template<int K, int LDC, int EPI, int CVTA>
__global__ __launch_bounds__(512) void gemm_mfma(
    const void* __restrict__ Av,            // [M][K] f32 (CVTA) or bf16
    const unsigned short* __restrict__ Bt,  // [N][K] bf16
    const float* __restrict__ bias,
    void* __restrict__ Cv)
{
    const int m0 = blockIdx.x * 128;
    const int n0 = blockIdx.y * 256;
    const int tid = threadIdx.x;
    const int lane = tid & 63;
    const int w = tid >> 6;
    const int wr = w >> 2;          // 0..1 (M)
    const int wn = w & 3;           // 0..3 (N), owns cols wn*64..+64
    __shared__ unsigned short lA[128 * 64];   // 16KB, 1024 units
    __shared__ unsigned short lB[256 * 64];   // 32KB, 2048 units

    // A staging: 1024 units, 2 per thread
    const int ca0 = tid,       ra0 = ca0 >> 3, ga0 = ca0 & 7;
    const int ca1 = tid + 512, ra1 = ca1 >> 3, ga1 = ca1 & 7;
    const int ua0 = (((ra0 >> 4) * 8 + ga0) * 16) + (ra0 & 15);
    const int ua1 = (((ra1 >> 4) * 8 + ga1) * 16) + (ra1 & 15);
    int am0 = m0 + ra0; if (am0 >= N_NODES) am0 = N_NODES - 1;
    int am1 = m0 + ra1; if (am1 >= N_NODES) am1 = N_NODES - 1;
    const float* Af0 = nullptr; const float* Af1 = nullptr;
    const unsigned short* Ab0 = nullptr; const unsigned short* Ab1 = nullptr;
    if constexpr (CVTA) {
        const float* Af = (const float*)Av;
        Af0 = Af + (size_t)am0 * K + ga0 * 8;
        Af1 = Af + (size_t)am1 * K + ga1 * 8;
    } else {
        const unsigned short* Ab = (const unsigned short*)Av;
        Ab0 = Ab + (size_t)am0 * K + ga0 * 8;
        Ab1 = Ab + (size_t)am1 * K + ga1 * 8;
    }

    // B staging: 2048 units, 4 per thread
    const unsigned short* Bp[4];
    int ub[4];
    #pragma unroll
    for (int j = 0; j < 4; ++j) {
        const int cb = tid + j * 512;
        const int rb = cb >> 3, gb = cb & 7;
        ub[j] = (((rb >> 4) * 8 + gb) * 16) + (rb & 15);
        Bp[j] = Bt + (size_t)(n0 + rb) * K + gb * 8;
    }

    f32x4 acc[4][4];
    #pragma unroll
    for (int t = 0; t < 4; ++t)
        #pragma unroll
        for (int n = 0; n < 4; ++n) acc[t][n] = (f32x4){0,0,0,0};

    for (int k0 = 0; k0 < K; k0 += 64) {
        if constexpr (CVTA) {
            *(bf16x8*)(lA + ua0 * 8) = cvt8(Af0 + k0);
            *(bf16x8*)(lA + ua1 * 8) = cvt8(Af1 + k0);
        } else {
            *(bf16x8*)(lA + ua0 * 8) = *(const bf16x8*)(Ab0 + k0);
            *(bf16x8*)(lA + ua1 * 8) = *(const bf16x8*)(Ab1 + k0);
        }
        #pragma unroll
        for (int j = 0; j < 4; ++j)
            *(bf16x8*)(lB + ub[j] * 8) = *(const bf16x8*)(Bp[j] + k0);
        __syncthreads();
        #pragma unroll
        for (int kk = 0; kk < 2; ++kk) {
            bf16x8 bfr[4];
            #pragma unroll
            for (int n = 0; n < 4; ++n)
                bfr[n] = *(const bf16x8*)(lB + ((wn * 4 + n) * 128 + kk * 64 + lane) * 8);
            #pragma unroll
            for (int t = 0; t < 4; ++t) {
                const bf16x8 afr = *(const bf16x8*)(lA + ((wr * 4 + t) * 128 + kk * 64 + lane) * 8);
                #pragma unroll
                for (int n = 0; n < 4; ++n)
                    acc[t][n] = __builtin_amdgcn_mfma_f32_16x16x32_bf16(afr, bfr[n], acc[t][n], 0, 0, 0);
            }
        }
        __syncthreads();
    }

    #pragma unroll
    for (int n = 0; n < 4; ++n) {
        const int col = n0 + wn * 64 + n * 16 + (lane & 15);
        float b = 0.0f;
        if (EPI == 1) b = bias[col];
        #pragma unroll
        for (int t = 0; t < 4; ++t) {
            #pragma unroll
            for (int r = 0; r < 4; ++r) {
                const int m = m0 + wr * 64 + t * 16 + ((lane >> 4) << 2) + r;
                if (m < N_NODES) {
                    const float v = acc[t][n][r];
                    if (EPI == 0) {
                        ((unsigned short*)Cv)[(size_t)m * LDC + col] = f2bf(v);
                    } else {
                        float z = v + b;
                        ((float*)Cv)[(size_t)m * LDC + col] = (z > 0.0f) ? z : expm1f(z);
                    }
                }
            }
        }
    }
}

// ---------------------------------------------------------------------------
// Fused segment kernel v6: v5 (inline s-projection + one-time f32 convert +
// __expf, validated R17) with a 2-stage REGISTER PIPELINE over 4-edge
// batches: batch b+1's four h-rows are loaded before batch b's compute
// (loads depend only on register my_src — no barriers), and batch 0's
// loads are issued before the s_tgt computation. Doubles per-wave memory-
// level parallelism; pure reorder, identical math.
// All __shfl at wave-uniform control flow (R6 lesson); the pipeline
// conditions (nb4, more) are wave-uniform since cnt is wave-uniform.
// ---------------------------------------------------------------------------
__global__ __launch_bounds__(256) void segment_kernel(
    const int* __restrict__ deg, const int* __restrict__ csr,
    const float* __restrict__ a,
    const unsigned short* __restrict__ hb, unsigned short* __restrict__ accb)
{
    const int t = blockIdx.x * 4 + (threadIdx.x >> 6);
    const int lane = threadIdx.x & 63;
    if (t >= N_NODES) return;
    const int myhead = lane >> 3;
    const int seg = lane & 7;

    // hoist this lane's a-slices to registers (a is 4KB, L1-resident)
    float ra[8], rq[8];
    #pragma unroll
    for (int j = 0; j < 8; ++j) {
        ra[j] = a[myhead * 128 + seg * 8 + j];        // a_src slice
        rq[j] = a[myhead * 128 + 64 + seg * 8 + j];   // a_tgt slice
    }

    const int cnt = min(deg[t], BUCKET);
    int my_src = 0;
    if (lane < cnt) my_src = csr[t * BUCKET + lane];

    const int nb4 = cnt & ~3;        // edges covered by full 4-batches

    // ---- pipeline prologue: issue batch-0 loads before st compute ----
    bf16x8 hv[4];
    if (nb4 > 0) {                    // wave-uniform
        #pragma unroll
        for (int u = 0; u < 4; ++u) {
            const int sr = __shfl(my_src, u);
            hv[u] = *(const bf16x8*)(hb + (size_t)sr * 512 + lane * 8);
        }
    }

    // s_tgt for this target's head (overlaps batch-0 loads)
    float st;
    {
        const bf16x8 ht = *(const bf16x8*)(hb + (size_t)t * 512 + lane * 8);
        float q = 0.0f;
        #pragma unroll
        for (int j = 0; j < 8; ++j)
            q = fmaf(bf2f((unsigned short)ht[j]), rq[j], q);
        q += __shfl_xor(q, 1);
        q += __shfl_xor(q, 2);
        q += __shfl_xor(q, 4);
        st = q;
    }

    float dsum = 0.0f;
    float msg[8] = {};
    for (int b = 0; b < nb4; b += 4) {
        // prefetch batch b+4 while batch b computes (wave-uniform cond)
        bf16x8 hvn[4];
        const bool more = (b + 8 <= nb4);
        if (more) {
            #pragma unroll
            for (int u = 0; u < 4; ++u) {
                const int sr = __shfl(my_src, b + 4 + u);
                hvn[u] = *(const bf16x8*)(hb + (size_t)sr * 512 + lane * 8);
            }
        }
        // convert current batch ONCE to f32; reused by dot and msg loops
        float hf[4][8];
        #pragma unroll
        for (int u = 0; u < 4; ++u)
            #pragma unroll
            for (int j = 0; j < 8; ++j)
                hf[u][j] = bf2f((unsigned short)hv[u][j]);
        float p[4];
        #pragma unroll
        for (int u = 0; u < 4; ++u) {
            float s = 0.0f;
            #pragma unroll
            for (int j = 0; j < 8; ++j)
                s = fmaf(hf[u][j], ra[j], s);
            p[u] = s;
        }
        #pragma unroll
        for (int u = 0; u < 4; ++u) {
            p[u] += __shfl_xor(p[u], 1);
            p[u] += __shfl_xor(p[u], 2);
            p[u] += __shfl_xor(p[u], 4);
        }
        #pragma unroll
        for (int u = 0; u < 4; ++u) {
            float v = p[u] + st;
            v = (v >= 0.0f) ? v : NEG_SLOPE * v;
            const float pv = __expf(v);
            dsum += pv;
            #pragma unroll
            for (int j = 0; j < 8; ++j)
                msg[j] = fmaf(hf[u][j], pv, msg[j]);
        }
        if (more) {
            #pragma unroll
            for (int u = 0; u < 4; ++u) hv[u] = hvn[u];
        }
    }
    // tail (cnt - nb4 < 4 edges)
    for (int i = nb4; i < cnt; ++i) {
        const int src = __shfl(my_src, i);
        const bf16x8 hvt = *(const bf16x8*)(hb + (size_t)src * 512 + lane * 8);
        float hf[8];
        #pragma unroll
        for (int j = 0; j < 8; ++j) hf[j] = bf2f((unsigned short)hvt[j]);
        float s = 0.0f;
        #pragma unroll
        for (int j = 0; j < 8; ++j)
            s = fmaf(hf[j], ra[j], s);
        s += __shfl_xor(s, 1);
        s += __shfl_xor(s, 2);
        s += __shfl_xor(s, 4);
        float v = s + st;
        v = (v >= 0.0f) ? v : NEG_SLOPE * v;
        const float pv = __expf(v);
        dsum += pv;
        #pragma unroll
        for (int j = 0; j < 8; ++j)
            msg[j] = fmaf(hf[j], pv, msg[j]);
    }
    const float d = dsum + 1e-16f;   // all lanes of a head group hold the same dsum
    bf16x8 ov;
    #pragma unroll
    for (int j = 0; j < 8; ++j) ov[j] = (short)f2bf(msg[j] / d);
    *(bf16x8*)(accb + (size_t)t * 512 + lane * 8) = ov;
}

// ---------------------------------------------------------------------------
extern "C" void kernel_launch(void* const* d_in, const int* in_sizes, int n_in,
                              void* d_out, int out_size, void* d_ws, size_t ws_size,
                              hipStream_t stream) {
    const float* x   = (const float*)d_in[0];
    const int*   ei  = (const int*)d_in[1];
    const float* W   = (const float*)d_in[2];
    const float* a   = (const float*)d_in[3];
    const float* Wo  = (const float*)d_in[4];
    const float* bo  = (const float*)d_in[5];
    float* out = (float*)d_out;

    // workspace: hb | accb | Wt | Wot | deg | csr(bucket)
    unsigned short* hb   = (unsigned short*)d_ws;
    const size_t hsz = (size_t)N_NODES * HEADS * HID;        // 25.6M elems
    unsigned short* accb = hb + hsz;
    unsigned short* Wt   = accb + hsz;
    unsigned short* Wot  = Wt + (size_t)HEADS * HID * IN_DIM;
    int* deg = (int*)(Wot + (size_t)(HEADS * HID) * OUT_DIM);
    int* csr = deg + N_NODES;                // [N_NODES][BUCKET] = 12.8MB

    hipMemsetAsync(deg, 0, N_NODES * sizeof(int), stream);

    prep_kernel<<<CVTW_BLOCKS + CVTWO_BLOCKS + FILL_BLOCKS, 256, 0, stream>>>(
        W, Wt, Wo, Wot, ei, deg, csr);

    // h = x @ W  (bf16 out), A = x f32 converted in staging (CVTA=1)
    dim3 g1((N_NODES + 127) / 128, (HEADS * HID) / 256);   // 391 x 2
    gemm_mfma<IN_DIM, HEADS * HID, 0, 1><<<g1, 512, 0, stream>>>(
        x, Wt, nullptr, hb);

    segment_kernel<<<(N_NODES + 3) / 4, 256, 0, stream>>>(
        deg, csr, a, hb, accb);

    // out = elu(acc @ Wo + bo), A = accb bf16 (CVTA=0)
    dim3 g5((N_NODES + 127) / 128, OUT_DIM / 256);         // 391 x 1
    gemm_mfma<HEADS * HID, OUT_DIM, 1, 0><<<g5, 512, 0, stream>>>(
        accb, Wot, bo, out);
}

// Round 19
// 192.037 us; speedup vs baseline: 1.0218x; 1.0218x over previous
//
#include <hip/hip_runtime.h>
#include <hip/hip_bf16.h>
#include <math.h>

#define N_NODES 50000
#define N_EDGES 400000
#define IN_DIM 256
#define HID 64
#define HEADS 8
#define OUT_DIM 256
#define NEG_SLOPE 0.2f
#define BUCKET 64   // max in-degree capacity; P(exceed)<1e-30 for this input

// prep ranges: cvt_w | cvt_wo | fillhist
#define CVTW_BLOCKS 512               // 131072/256 exact
#define CVTWO_BLOCKS 512
#define FILL_BLOCKS 1563

typedef __attribute__((ext_vector_type(8))) short bf16x8;
typedef __attribute__((ext_vector_type(4))) float f32x4;

// RNE float->bf16
static __device__ __forceinline__ unsigned short f2bf(float f) {
    unsigned int u = __float_as_uint(f);
    unsigned int r = (u + 0x7fffu + ((u >> 16) & 1u)) >> 16;
    return (unsigned short)r;
}
static __device__ __forceinline__ float bf2f(unsigned short s) {
    return __uint_as_float((unsigned int)s << 16);
}
// convert 8 contiguous floats -> bf16x8
static __device__ __forceinline__ bf16x8 cvt8(const float* __restrict__ p) {
    bf16x8 r;
    #pragma unroll
    for (int j = 0; j < 8; ++j) r[j] = (short)f2bf(p[j]);
    return r;
}

// ---------------------------------------------------------------------------
// Fused prologue: cvt_w | cvt_wo | bucket-CSR fillhist by blockIdx range.
// ---------------------------------------------------------------------------
__global__ __launch_bounds__(256) void prep_kernel(
    const float* __restrict__ W, unsigned short* __restrict__ Wt,
    const float* __restrict__ Wo, unsigned short* __restrict__ Wot,
    const int* __restrict__ ei, int* __restrict__ deg,
    int* __restrict__ csr)
{
    const int b = blockIdx.x;
    if (b < CVTW_BLOCKS) {
        // W[hd][k][o] -> Wt[hd*64+o][k]
        const int i = b * 256 + threadIdx.x;
        const int hd = i >> 14;
        const int o  = (i >> 8) & 63;
        const int k  = i & 255;
        Wt[i] = f2bf(W[((size_t)hd * IN_DIM + k) * HID + o]);
    } else if (b < CVTW_BLOCKS + CVTWO_BLOCKS) {
        // Wo[k][n] -> Wot[n][k]
        const int i = (b - CVTW_BLOCKS) * 256 + threadIdx.x;
        const int n = i >> 9;
        const int k = i & 511;
        Wot[i] = f2bf(Wo[(size_t)k * OUT_DIM + n]);
    } else {
        // bucket-CSR: pos = atomicAdd(deg[tgt]); csr[tgt*BUCKET+pos] = src
        const int e = (b - CVTW_BLOCKS - CVTWO_BLOCKS) * 256 + threadIdx.x;
        if (e < N_EDGES) {
            const int src = ei[e];
            const int tgt = ei[N_EDGES + e];
            const int pos = atomicAdd(&deg[tgt], 1);
            if (pos < BUCKET) csr[tgt * BUCKET + pos] = src;
        }
    }
}

// ---------------------------------------------------------------------------
// Unified MFMA GEMM v3 (validated R13-R17): C[M][LDC] = A[M][K] @ Bt[N][K]^T
// Tile 128x256, BK=64, 512 thr = 8 waves (2M x 4N), acc[4][4],
// 32 MFMAs per barrier pair. CVTA=1: A f32 -> bf16 in staging.
// Fragment-order LDS: unit(row,g)=((row>>4)*8+g)*16+(row&15); frag read
// = units R*128 + kk*64 + lane (lane-linear, conflict-free).
// EPI 0: store C bf16.  EPI 1: +bias, elu, store f32.
// ---------------------------------------------------------------------------
template<int K, int LDC, int EPI, int CVTA>
__global__ __launch_bounds__(512) void gemm_mfma(
    const void* __restrict__ Av,            // [M][K] f32 (CVTA) or bf16
    const unsigned short* __restrict__ Bt,  // [N][K] bf16
    const float* __restrict__ bias,
    void* __restrict__ Cv)
{
    const int m0 = blockIdx.x * 128;
    const int n0 = blockIdx.y * 256;
    const int tid = threadIdx.x;
    const int lane = tid & 63;
    const int w = tid >> 6;
    const int wr = w >> 2;          // 0..1 (M)
    const int wn = w & 3;           // 0..3 (N), owns cols wn*64..+64
    __shared__ unsigned short lA[128 * 64];   // 16KB, 1024 units
    __shared__ unsigned short lB[256 * 64];   // 32KB, 2048 units

    // A staging: 1024 units, 2 per thread
    const int ca0 = tid,       ra0 = ca0 >> 3, ga0 = ca0 & 7;
    const int ca1 = tid + 512, ra1 = ca1 >> 3, ga1 = ca1 & 7;
    const int ua0 = (((ra0 >> 4) * 8 + ga0) * 16) + (ra0 & 15);
    const int ua1 = (((ra1 >> 4) * 8 + ga1) * 16) + (ra1 & 15);
    int am0 = m0 + ra0; if (am0 >= N_NODES) am0 = N_NODES - 1;
    int am1 = m0 + ra1; if (am1 >= N_NODES) am1 = N_NODES - 1;
    const float* Af0 = nullptr; const float* Af1 = nullptr;
    const unsigned short* Ab0 = nullptr; const unsigned short* Ab1 = nullptr;
    if constexpr (CVTA) {
        const float* Af = (const float*)Av;
        Af0 = Af + (size_t)am0 * K + ga0 * 8;
        Af1 = Af + (size_t)am1 * K + ga1 * 8;
    } else {
        const unsigned short* Ab = (const unsigned short*)Av;
        Ab0 = Ab + (size_t)am0 * K + ga0 * 8;
        Ab1 = Ab + (size_t)am1 * K + ga1 * 8;
    }

    // B staging: 2048 units, 4 per thread
    const unsigned short* Bp[4];
    int ub[4];
    #pragma unroll
    for (int j = 0; j < 4; ++j) {
        const int cb = tid + j * 512;
        const int rb = cb >> 3, gb = cb & 7;
        ub[j] = (((rb >> 4) * 8 + gb) * 16) + (rb & 15);
        Bp[j] = Bt + (size_t)(n0 + rb) * K + gb * 8;
    }

    f32x4 acc[4][4];
    #pragma unroll
    for (int t = 0; t < 4; ++t)
        #pragma unroll
        for (int n = 0; n < 4; ++n) acc[t][n] = (f32x4){0,0,0,0};

    for (int k0 = 0; k0 < K; k0 += 64) {
        if constexpr (CVTA) {
            *(bf16x8*)(lA + ua0 * 8) = cvt8(Af0 + k0);
            *(bf16x8*)(lA + ua1 * 8) = cvt8(Af1 + k0);
        } else {
            *(bf16x8*)(lA + ua0 * 8) = *(const bf16x8*)(Ab0 + k0);
            *(bf16x8*)(lA + ua1 * 8) = *(const bf16x8*)(Ab1 + k0);
        }
        #pragma unroll
        for (int j = 0; j < 4; ++j)
            *(bf16x8*)(lB + ub[j] * 8) = *(const bf16x8*)(Bp[j] + k0);
        __syncthreads();
        #pragma unroll
        for (int kk = 0; kk < 2; ++kk) {
            bf16x8 bfr[4];
            #pragma unroll
            for (int n = 0; n < 4; ++n)
                bfr[n] = *(const bf16x8*)(lB + ((wn * 4 + n) * 128 + kk * 64 + lane) * 8);
            #pragma unroll
            for (int t = 0; t < 4; ++t) {
                const bf16x8 afr = *(const bf16x8*)(lA + ((wr * 4 + t) * 128 + kk * 64 + lane) * 8);
                #pragma unroll
                for (int n = 0; n < 4; ++n)
                    acc[t][n] = __builtin_amdgcn_mfma_f32_16x16x32_bf16(afr, bfr[n], acc[t][n], 0, 0, 0);
            }
        }
        __syncthreads();
    }

    #pragma unroll
    for (int n = 0; n < 4; ++n) {
        const int col = n0 + wn * 64 + n * 16 + (lane & 15);
        float b = 0.0f;
        if (EPI == 1) b = bias[col];
        #pragma unroll
        for (int t = 0; t < 4; ++t) {
            #pragma unroll
            for (int r = 0; r < 4; ++r) {
                const int m = m0 + wr * 64 + t * 16 + ((lane >> 4) << 2) + r;
                if (m < N_NODES) {
                    const float v = acc[t][n][r];
                    if (EPI == 0) {
                        ((unsigned short*)Cv)[(size_t)m * LDC + col] = f2bf(v);
                    } else {
                        float z = v + b;
                        ((float*)Cv)[(size_t)m * LDC + col] = (z > 0.0f) ? z : expm1f(z);
                    }
                }
            }
        }
    }
}

// ---------------------------------------------------------------------------
// Fused segment kernel v5 (validated R17 — best measured point): inline
// s-projection, one-time bf16->f32 convert per gathered row, native __expf.
// All __shfl at wave-uniform control flow (R6 lesson).
// (R18's 2-stage register pipeline regressed: +12 VGPR -> occupancy 42->33%,
// TLP loss outweighed ILP gain. Reverted.)
// ---------------------------------------------------------------------------
__global__ __launch_bounds__(256) void segment_kernel(
    const int* __restrict__ deg, const int* __restrict__ csr,
    const float* __restrict__ a,
    const unsigned short* __restrict__ hb, unsigned short* __restrict__ accb)
{
    const int t = blockIdx.x * 4 + (threadIdx.x >> 6);
    const int lane = threadIdx.x & 63;
    if (t >= N_NODES) return;
    const int myhead = lane >> 3;
    const int seg = lane & 7;

    // hoist this lane's a-slices to registers (a is 4KB, L1-resident)
    float ra[8], rq[8];
    #pragma unroll
    for (int j = 0; j < 8; ++j) {
        ra[j] = a[myhead * 128 + seg * 8 + j];        // a_src slice
        rq[j] = a[myhead * 128 + 64 + seg * 8 + j];   // a_tgt slice
    }

    // s_tgt for this target's head
    float st;
    {
        const bf16x8 ht = *(const bf16x8*)(hb + (size_t)t * 512 + lane * 8);
        float q = 0.0f;
        #pragma unroll
        for (int j = 0; j < 8; ++j)
            q = fmaf(bf2f((unsigned short)ht[j]), rq[j], q);
        q += __shfl_xor(q, 1);
        q += __shfl_xor(q, 2);
        q += __shfl_xor(q, 4);
        st = q;
    }

    const int cnt = min(deg[t], BUCKET);
    int my_src = 0;
    if (lane < cnt) my_src = csr[t * BUCKET + lane];

    float dsum = 0.0f;
    float msg[8] = {};
    int i = 0;
    for (; i + 4 <= cnt; i += 4) {
        int sr[4]; bf16x8 hv[4];
        #pragma unroll
        for (int u = 0; u < 4; ++u) sr[u] = __shfl(my_src, i + u);
        #pragma unroll
        for (int u = 0; u < 4; ++u)
            hv[u] = *(const bf16x8*)(hb + (size_t)sr[u] * 512 + lane * 8);
        // convert ONCE to f32; reused by dot and msg loops
        float hf[4][8];
        #pragma unroll
        for (int u = 0; u < 4; ++u)
            #pragma unroll
            for (int j = 0; j < 8; ++j)
                hf[u][j] = bf2f((unsigned short)hv[u][j]);
        float p[4];
        #pragma unroll
        for (int u = 0; u < 4; ++u) {
            float s = 0.0f;
            #pragma unroll
            for (int j = 0; j < 8; ++j)
                s = fmaf(hf[u][j], ra[j], s);
            p[u] = s;
        }
        #pragma unroll
        for (int u = 0; u < 4; ++u) {
            p[u] += __shfl_xor(p[u], 1);
            p[u] += __shfl_xor(p[u], 2);
            p[u] += __shfl_xor(p[u], 4);
        }
        #pragma unroll
        for (int u = 0; u < 4; ++u) {
            float v = p[u] + st;
            v = (v >= 0.0f) ? v : NEG_SLOPE * v;
            const float pv = __expf(v);
            dsum += pv;
            #pragma unroll
            for (int j = 0; j < 8; ++j)
                msg[j] = fmaf(hf[u][j], pv, msg[j]);
        }
    }
    for (; i < cnt; ++i) {
        const int src = __shfl(my_src, i);
        const bf16x8 hv = *(const bf16x8*)(hb + (size_t)src * 512 + lane * 8);
        float hf[8];
        #pragma unroll
        for (int j = 0; j < 8; ++j) hf[j] = bf2f((unsigned short)hv[j]);
        float s = 0.0f;
        #pragma unroll
        for (int j = 0; j < 8; ++j)
            s = fmaf(hf[j], ra[j], s);
        s += __shfl_xor(s, 1);
        s += __shfl_xor(s, 2);
        s += __shfl_xor(s, 4);
        float v = s + st;
        v = (v >= 0.0f) ? v : NEG_SLOPE * v;
        const float pv = __expf(v);
        dsum += pv;
        #pragma unroll
        for (int j = 0; j < 8; ++j)
            msg[j] = fmaf(hf[j], pv, msg[j]);
    }
    const float d = dsum + 1e-16f;   // all lanes of a head group hold the same dsum
    bf16x8 ov;
    #pragma unroll
    for (int j = 0; j < 8; ++j) ov[j] = (short)f2bf(msg[j] / d);
    *(bf16x8*)(accb + (size_t)t * 512 + lane * 8) = ov;
}

// ---------------------------------------------------------------------------
extern "C" void kernel_launch(void* const* d_in, const int* in_sizes, int n_in,
                              void* d_out, int out_size, void* d_ws, size_t ws_size,
                              hipStream_t stream) {
    const float* x   = (const float*)d_in[0];
    const int*   ei  = (const int*)d_in[1];
    const float* W   = (const float*)d_in[2];
    const float* a   = (const float*)d_in[3];
    const float* Wo  = (const float*)d_in[4];
    const float* bo  = (const float*)d_in[5];
    float* out = (float*)d_out;

    // workspace: hb | accb | Wt | Wot | deg | csr(bucket)
    unsigned short* hb   = (unsigned short*)d_ws;
    const size_t hsz = (size_t)N_NODES * HEADS * HID;        // 25.6M elems
    unsigned short* accb = hb + hsz;
    unsigned short* Wt   = accb + hsz;
    unsigned short* Wot  = Wt + (size_t)HEADS * HID * IN_DIM;
    int* deg = (int*)(Wot + (size_t)(HEADS * HID) * OUT_DIM);
    int* csr = deg + N_NODES;                // [N_NODES][BUCKET] = 12.8MB

    hipMemsetAsync(deg, 0, N_NODES * sizeof(int), stream);

    prep_kernel<<<CVTW_BLOCKS + CVTWO_BLOCKS + FILL_BLOCKS, 256, 0, stream>>>(
        W, Wt, Wo, Wot, ei, deg, csr);

    // h = x @ W  (bf16 out), A = x f32 converted in staging (CVTA=1)
    dim3 g1((N_NODES + 127) / 128, (HEADS * HID) / 256);   // 391 x 2
    gemm_mfma<IN_DIM, HEADS * HID, 0, 1><<<g1, 512, 0, stream>>>(
        x, Wt, nullptr, hb);

    segment_kernel<<<(N_NODES + 3) / 4, 256, 0, stream>>>(
        deg, csr, a, hb, accb);

    // out = elu(acc @ Wo + bo), A = accb bf16 (CVTA=0)
    dim3 g5((N_NODES + 127) / 128, OUT_DIM / 256);         // 391 x 1
    gemm_mfma<HEADS * HID, OUT_DIM, 1, 0><<<g5, 512, 0, stream>>>(
        accb, Wot, bo, out);
}